// Round 1
// baseline (9742.513 us; speedup 1.0000x reference)
//
#include <hip/hip_runtime.h>

#define NELEM  200000
#define NREACT 100000
#define EDIM   200
#define RDIM   128
#define F0     328      // EDIM + RDIM
#define NH     3
#define RT     16       // rows per block tile (NELEM % RT == 0)
#define NT     256      // threads per block

// -------------------- fused MLP layer (fp32, VALU) --------------------
// bufIn: RT x FIN activations in LDS. bufOut: RT x O.
// RESMODE: 1 = identity residual (FIN==O), 2 = projection residual (Wres)
template<int FIN, int O, int RESMODE>
__device__ __forceinline__ void layer_gemm(
    const float* __restrict__ bufIn, float* __restrict__ bufOut,
    const float* __restrict__ W, const float* __restrict__ bias,
    const float* __restrict__ Wres, int tid)
{
    constexpr int G   = NT / O;     // thread groups over rows
    constexpr int RPT = RT / G;     // rows per thread
    constexpr int F4  = FIN / 4;
    const int o  = tid & (O - 1);
    const int r0 = (tid / O) * RPT;
    const float4* in4 = reinterpret_cast<const float4*>(bufIn + r0 * FIN);

    float acc[RPT];
    float accr[RPT];
#pragma unroll
    for (int i = 0; i < RPT; ++i) { acc[i] = 0.0f; accr[i] = 0.0f; }

    const float* wp = W + o;
    for (int f4 = 0; f4 < F4; ++f4) {
        const int fb = f4 * 4;
        float w0 = wp[(fb + 0) * O];
        float w1 = wp[(fb + 1) * O];
        float w2 = wp[(fb + 2) * O];
        float w3 = wp[(fb + 3) * O];
        if constexpr (RESMODE == 2) {
            const float* wrp = Wres + o;
            float u0 = wrp[(fb + 0) * O];
            float u1 = wrp[(fb + 1) * O];
            float u2 = wrp[(fb + 2) * O];
            float u3 = wrp[(fb + 3) * O];
#pragma unroll
            for (int i = 0; i < RPT; ++i) {
                float4 x = in4[i * F4 + f4];
                acc[i]  = fmaf(x.x, w0, acc[i]);
                acc[i]  = fmaf(x.y, w1, acc[i]);
                acc[i]  = fmaf(x.z, w2, acc[i]);
                acc[i]  = fmaf(x.w, w3, acc[i]);
                accr[i] = fmaf(x.x, u0, accr[i]);
                accr[i] = fmaf(x.y, u1, accr[i]);
                accr[i] = fmaf(x.z, u2, accr[i]);
                accr[i] = fmaf(x.w, u3, accr[i]);
            }
        } else {
#pragma unroll
            for (int i = 0; i < RPT; ++i) {
                float4 x = in4[i * F4 + f4];
                acc[i] = fmaf(x.x, w0, acc[i]);
                acc[i] = fmaf(x.y, w1, acc[i]);
                acc[i] = fmaf(x.z, w2, acc[i]);
                acc[i] = fmaf(x.w, w3, acc[i]);
            }
        }
    }
    const float b = bias[o];
#pragma unroll
    for (int i = 0; i < RPT; ++i) {
        float z = fmaxf(acc[i] + b, 0.0f);
        if constexpr (RESMODE == 1) z += bufIn[(r0 + i) * FIN + o];
        else                        z += accr[i];
        bufOut[(r0 + i) * O + o] = z;
    }
}

// -------------------- main fused MLP kernel --------------------
__global__ __launch_bounds__(NT)
void mlp_kernel(const float* __restrict__ elem, const int* __restrict__ ridx,
                const float* __restrict__ embed,
                const float* __restrict__ fcW0, const float* __restrict__ fcb0,
                const float* __restrict__ fcW1, const float* __restrict__ fcb1,
                const float* __restrict__ fcW2, const float* __restrict__ fcb2,
                const float* __restrict__ fcW3, const float* __restrict__ fcb3,
                const float* __restrict__ fcW4, const float* __restrict__ fcb4,
                const float* __restrict__ fcW5, const float* __restrict__ fcb5,
                const float* __restrict__ fcW6, const float* __restrict__ fcb6,
                const float* __restrict__ resW0, const float* __restrict__ resW4,
                const float* __restrict__ resW6,
                const float* __restrict__ outW, const float* __restrict__ outb,
                float* __restrict__ gate, unsigned int* __restrict__ segmax)
{
    __shared__ float4 sA4[RT * F0 / 4];
    __shared__ float4 sB4[RT * 256 / 4];
    __shared__ int    sidx[RT];
    float* bufA = reinterpret_cast<float*>(sA4);
    float* bufB = reinterpret_cast<float*>(sB4);

    const int tid  = threadIdx.x;
    const int head = blockIdx.y;
    const int row0 = blockIdx.x * RT;

    if (tid < RT) sidx[tid] = ridx[row0 + tid];
    __syncthreads();

    // stage concat(elem_fea, embed[idx]) for 16 rows into bufA (RT x 328)
    for (int r = 0; r < RT; ++r) {
        const float* src = elem + (size_t)(row0 + r) * EDIM;
        for (int f = tid; f < EDIM; f += NT) bufA[r * F0 + f] = src[f];
        const float* se = embed + (size_t)sidx[r] * RDIM;
        if (tid < RDIM) bufA[r * F0 + EDIM + tid] = se[tid];
    }
    __syncthreads();

    const size_t h = head;
    layer_gemm<F0, 256, 2>(bufA, bufB, fcW0 + h * F0 * 256, fcb0 + h * 256,
                           resW0 + h * F0 * 256, tid);
    __syncthreads();
    layer_gemm<256, 256, 1>(bufB, bufA, fcW1 + h * 65536, fcb1 + h * 256, nullptr, tid);
    __syncthreads();
    layer_gemm<256, 256, 1>(bufA, bufB, fcW2 + h * 65536, fcb2 + h * 256, nullptr, tid);
    __syncthreads();
    layer_gemm<256, 256, 1>(bufB, bufA, fcW3 + h * 65536, fcb3 + h * 256, nullptr, tid);
    __syncthreads();
    layer_gemm<256, 128, 2>(bufA, bufB, fcW4 + h * 32768, fcb4 + h * 128,
                            resW4 + h * 32768, tid);
    __syncthreads();
    layer_gemm<128, 128, 1>(bufB, bufA, fcW5 + h * 16384, fcb5 + h * 128, nullptr, tid);
    __syncthreads();
    layer_gemm<128, 64, 2>(bufA, bufB, fcW6 + h * 8192, fcb6 + h * 64,
                           resW6 + h * 8192, tid);
    __syncthreads();

    // gate = h @ outW + outb, one thread per row
    if (tid < RT) {
        const float* hv = bufB + tid * 64;
        const float* wv = outW + h * 64;
        float g = outb[head];
#pragma unroll
        for (int f = 0; f < 64; ++f) g = fmaf(hv[f], wv[f], g);
        gate[head * NELEM + row0 + tid] = g;
        // order-preserving uint encoding for float atomicMax
        unsigned int bits = __float_as_uint(g);
        unsigned int enc  = (bits & 0x80000000u) ? ~bits : (bits | 0x80000000u);
        atomicMax(&segmax[head * NREACT + sidx[tid]], enc);
    }
}

// -------------------- softmax phases --------------------
__global__ void phase2_kernel(float* __restrict__ gate, const int* __restrict__ ridx,
                              const unsigned int* __restrict__ segmax,
                              float* __restrict__ segsum)
{
    int i = blockIdx.x * blockDim.x + threadIdx.x;
    if (i >= NH * NELEM) return;
    int h = i / NELEM;
    int n = i - h * NELEM;
    int j = ridx[n];
    unsigned int enc  = segmax[h * NREACT + j];
    unsigned int bits = (enc & 0x80000000u) ? (enc & 0x7FFFFFFFu) : ~enc;
    float m = __uint_as_float(bits);
    float e = __expf(gate[i] - m);
    gate[i] = e;
    atomicAdd(&segsum[h * NREACT + j], e);
}

__global__ void phase3_kernel(const float* __restrict__ gate, const int* __restrict__ ridx,
                              const float* __restrict__ segsum, float* __restrict__ out)
{
    int n = blockIdx.x * blockDim.x + threadIdx.x;
    if (n >= NELEM) return;
    int j = ridx[n];
    float s = 0.0f;
#pragma unroll
    for (int h = 0; h < NH; ++h)
        s += gate[h * NELEM + n] / (segsum[h * NREACT + j] + 1e-13f);
    out[n] = s * (1.0f / 3.0f);
}

// -------------------- launcher --------------------
extern "C" void kernel_launch(void* const* d_in, const int* in_sizes, int n_in,
                              void* d_out, int out_size, void* d_ws, size_t ws_size,
                              hipStream_t stream)
{
    const float* elem  = (const float*)d_in[0];
    const int*   ridx  = (const int*)  d_in[1];
    const float* embed = (const float*)d_in[2];
    const float* fcW0  = (const float*)d_in[3];
    const float* fcb0  = (const float*)d_in[4];
    const float* fcW1  = (const float*)d_in[5];
    const float* fcb1  = (const float*)d_in[6];
    const float* fcW2  = (const float*)d_in[7];
    const float* fcb2  = (const float*)d_in[8];
    const float* fcW3  = (const float*)d_in[9];
    const float* fcb3  = (const float*)d_in[10];
    const float* fcW4  = (const float*)d_in[11];
    const float* fcb4  = (const float*)d_in[12];
    const float* fcW5  = (const float*)d_in[13];
    const float* fcb5  = (const float*)d_in[14];
    const float* fcW6  = (const float*)d_in[15];
    const float* fcb6  = (const float*)d_in[16];
    const float* resW0 = (const float*)d_in[17];
    const float* resW4 = (const float*)d_in[18];
    const float* resW6 = (const float*)d_in[19];
    const float* outW  = (const float*)d_in[20];
    const float* outb  = (const float*)d_in[21];

    float*        gate   = (float*)d_ws;
    unsigned int* segmax = (unsigned int*)d_ws + (size_t)NH * NELEM;
    float*        segsum = (float*)d_ws + (size_t)NH * NELEM + (size_t)NH * NREACT;

    // zero segmax (uint 0 < any real float encoding) and segsum (0.0f)
    hipMemsetAsync((void*)segmax, 0, sizeof(unsigned int) * (size_t)NH * NREACT * 2, stream);

    dim3 grid(NELEM / RT, NH);
    mlp_kernel<<<grid, NT, 0, stream>>>(elem, ridx, embed,
                                        fcW0, fcb0, fcW1, fcb1, fcW2, fcb2, fcW3, fcb3,
                                        fcW4, fcb4, fcW5, fcb5, fcW6, fcb6,
                                        resW0, resW4, resW6, outW, outb,
                                        gate, segmax);

    int tot = NH * NELEM;
    phase2_kernel<<<(tot + 255) / 256, 256, 0, stream>>>(gate, ridx, segmax, segsum);
    phase3_kernel<<<(NELEM + 255) / 256, 256, 0, stream>>>(gate, ridx, segsum, (float*)d_out);
}

// Round 2
// 2207.606 us; speedup vs baseline: 4.4132x; 4.4132x over previous
//
#include <hip/hip_runtime.h>

#define NELEM  200000
#define NREACT 100000
#define EDIM   200
#define RDIM   128
#define F0     328
#define F0PAD  352      // K padded to multiple of 32 for layer 0
#define NH     3
#define MT     64       // rows per block tile (NELEM % MT == 0 -> 3125 blocks)
#define NT     256      // 4 waves

#define SA     360      // LDS stride (elems) for wide buffer (>=352), 720B = 2-way banks
#define SB     264      // LDS stride for 256-wide buffer, 528B = 2-way banks

typedef __attribute__((ext_vector_type(8))) short bf16x8;
typedef __attribute__((ext_vector_type(4))) float f32x4;

static __device__ __forceinline__ unsigned short f2bf(float f) {
    unsigned int u = __float_as_uint(f);
    u += 0x7FFFu + ((u >> 16) & 1u);   // round-to-nearest-even
    return (unsigned short)(u >> 16);
}
static __device__ __forceinline__ float bf2f(unsigned short h) {
    return __uint_as_float(((unsigned int)h) << 16);
}

// ---------------- weight convert + transpose prepass ----------------
// src: fp32 [H][K][N] -> dst: bf16 [H][N][Kpad] (zero-padded k >= K)
__global__ void wconv_kernel(const float* __restrict__ src, unsigned short* __restrict__ dst,
                             int K, int N, int Kpad)
{
    int b = blockIdx.x;            // over H*N
    int h = b / N, n = b - h * N;
    const float* s = src + (size_t)h * K * N + n;
    unsigned short* d = dst + (size_t)b * Kpad;
    for (int k = threadIdx.x; k < Kpad; k += blockDim.x)
        d[k] = (k < K) ? f2bf(s[(size_t)k * N]) : (unsigned short)0;
}

// ---------------- one MFMA layer ----------------
// aIn: LDS bf16 [MT][sIn], wave computes cols [n0, n0+TN*16)
// PROJ: projection residual from wRes; IDRES: identity residual from prev regs.
// prev updated to fp32 post-activation values (residual trunk stays fp32).
template<int TN, bool PROJ, bool IDRES>
__device__ __forceinline__ void layer(
    const unsigned short* __restrict__ aIn, int sIn,
    unsigned short* __restrict__ aOut, int sOut,
    const unsigned short* __restrict__ wFc,
    const unsigned short* __restrict__ wRes,
    const float* __restrict__ bias,
    int Kpad, int Ksteps, int n0,
    f32x4 prev[4][4], int lane)
{
    const int r = lane & 15, q = lane >> 4;
    f32x4 acc[4][TN];
    f32x4 racc[4][TN];
#pragma unroll
    for (int mt = 0; mt < 4; ++mt)
#pragma unroll
        for (int nt = 0; nt < TN; ++nt) {
            acc[mt][nt] = (f32x4){0.f, 0.f, 0.f, 0.f};
            if constexpr (PROJ) racc[mt][nt] = (f32x4){0.f, 0.f, 0.f, 0.f};
        }

    const unsigned short* aBase  = aIn + r * sIn + q * 8;
    const unsigned short* wBase  = wFc + ((size_t)n0 + r) * Kpad + q * 8;
    const unsigned short* wrBase = PROJ ? (wRes + ((size_t)n0 + r) * Kpad + q * 8) : nullptr;

    for (int kt = 0; kt < Ksteps; ++kt) {
        bf16x8 a[4];
#pragma unroll
        for (int mt = 0; mt < 4; ++mt)
            a[mt] = *(const bf16x8*)(aBase + mt * 16 * sIn + kt * 32);
#pragma unroll
        for (int nt = 0; nt < TN; ++nt) {
            bf16x8 b = *(const bf16x8*)(wBase + (size_t)nt * 16 * Kpad + kt * 32);
#pragma unroll
            for (int mt = 0; mt < 4; ++mt)
                acc[mt][nt] = __builtin_amdgcn_mfma_f32_16x16x32_bf16(a[mt], b, acc[mt][nt], 0, 0, 0);
            if constexpr (PROJ) {
                bf16x8 br = *(const bf16x8*)(wrBase + (size_t)nt * 16 * Kpad + kt * 32);
#pragma unroll
                for (int mt = 0; mt < 4; ++mt)
                    racc[mt][nt] = __builtin_amdgcn_mfma_f32_16x16x32_bf16(a[mt], br, racc[mt][nt], 0, 0, 0);
            }
        }
    }

    // epilogue: C/D layout col = lane&15, row = (lane>>4)*4 + reg
#pragma unroll
    for (int nt = 0; nt < TN; ++nt) {
        float b = bias[n0 + nt * 16 + r];
#pragma unroll
        for (int mt = 0; mt < 4; ++mt) {
#pragma unroll
            for (int i = 0; i < 4; ++i) {
                float z = fmaxf(acc[mt][nt][i] + b, 0.f);
                if constexpr (PROJ)       z += racc[mt][nt][i];
                else if constexpr (IDRES) z += prev[mt][nt][i];
                prev[mt][nt][i] = z;
                int m = mt * 16 + q * 4 + i;
                aOut[m * sOut + n0 + nt * 16 + r] = f2bf(z);
            }
        }
    }
}

// ---------------- fused MLP kernel ----------------
__global__ __launch_bounds__(NT, 2)
void mlp_mfma(const float* __restrict__ elem, const int* __restrict__ ridx,
              const float* __restrict__ embed,
              const unsigned short* __restrict__ wt_fc0, const unsigned short* __restrict__ wt_res0,
              const unsigned short* __restrict__ wt_fc1, const unsigned short* __restrict__ wt_fc2,
              const unsigned short* __restrict__ wt_fc3,
              const unsigned short* __restrict__ wt_fc4, const unsigned short* __restrict__ wt_res4,
              const unsigned short* __restrict__ wt_fc5,
              const unsigned short* __restrict__ wt_fc6, const unsigned short* __restrict__ wt_res6,
              const float* __restrict__ fcb0, const float* __restrict__ fcb1,
              const float* __restrict__ fcb2, const float* __restrict__ fcb3,
              const float* __restrict__ fcb4, const float* __restrict__ fcb5,
              const float* __restrict__ fcb6,
              const float* __restrict__ outW, const float* __restrict__ outb,
              float* __restrict__ gate, unsigned int* __restrict__ segmax)
{
    __shared__ __align__(16) unsigned short sX[MT * SA];   // 46080 B
    __shared__ __align__(16) unsigned short sY[MT * SB];   // 33792 B
    __shared__ int sidx[MT];

    const int tid = threadIdx.x, lane = tid & 63, wave = tid >> 6;
    const int head = blockIdx.y;
    const int row0 = blockIdx.x * MT;

    if (tid < MT) sidx[tid] = ridx[row0 + tid];
    __syncthreads();

    // stage concat(elem, embed[idx]) -> bf16 in sX, zero-pad k in [328,352)
    for (int r = wave; r < MT; r += 4) {
        const float* es = elem + (size_t)(row0 + r) * EDIM;
        const float* ms = embed + (size_t)sidx[r] * RDIM;
        for (int k = lane; k < F0PAD; k += 64) {
            float v = (k < EDIM) ? es[k] : (k < F0 ? ms[k - EDIM] : 0.f);
            sX[r * SA + k] = f2bf(v);
        }
    }
    __syncthreads();

    const size_t h = head;
    f32x4 prev[4][4];
    const int n64 = wave * 64, n32 = wave * 32, n16 = wave * 16;

    layer<4, true , false>(sX, SA, sY, SB, wt_fc0 + h * 256 * 352, wt_res0 + h * 256 * 352,
                           fcb0 + h * 256, 352, 11, n64, prev, lane);
    __syncthreads();
    layer<4, false, true >(sY, SB, sX, SA, wt_fc1 + h * 65536, nullptr,
                           fcb1 + h * 256, 256, 8, n64, prev, lane);
    __syncthreads();
    layer<4, false, true >(sX, SA, sY, SB, wt_fc2 + h * 65536, nullptr,
                           fcb2 + h * 256, 256, 8, n64, prev, lane);
    __syncthreads();
    layer<4, false, true >(sY, SB, sX, SA, wt_fc3 + h * 65536, nullptr,
                           fcb3 + h * 256, 256, 8, n64, prev, lane);
    __syncthreads();
    layer<2, true , false>(sX, SA, sY, SB, wt_fc4 + h * 32768, wt_res4 + h * 32768,
                           fcb4 + h * 128, 256, 8, n32, prev, lane);
    __syncthreads();
    layer<2, false, true >(sY, SB, sX, SA, wt_fc5 + h * 16384, nullptr,
                           fcb5 + h * 128, 128, 4, n32, prev, lane);
    __syncthreads();
    layer<1, true , false>(sX, SA, sY, SB, wt_fc6 + h * 8192, wt_res6 + h * 8192,
                           fcb6 + h * 64, 128, 4, n16, prev, lane);
    __syncthreads();

    // gate = h64 . outW + outb ; one thread per row
    if (tid < MT) {
        const unsigned short* hv = sY + tid * SB;
        const float* wv = outW + h * 64;
        float g = outb[head];
#pragma unroll
        for (int f = 0; f < 64; ++f) g = fmaf(bf2f(hv[f]), wv[f], g);
        gate[head * NELEM + row0 + tid] = g;
        unsigned int bits = __float_as_uint(g);
        unsigned int enc  = (bits & 0x80000000u) ? ~bits : (bits | 0x80000000u);
        atomicMax(&segmax[head * NREACT + sidx[tid]], enc);
    }
}

// ---------------- softmax phases ----------------
__global__ void phase2_kernel(float* __restrict__ gate, const int* __restrict__ ridx,
                              const unsigned int* __restrict__ segmax,
                              float* __restrict__ segsum)
{
    int i = blockIdx.x * blockDim.x + threadIdx.x;
    if (i >= NH * NELEM) return;
    int h = i / NELEM;
    int n = i - h * NELEM;
    int j = ridx[n];
    unsigned int enc  = segmax[h * NREACT + j];
    unsigned int bits = (enc & 0x80000000u) ? (enc & 0x7FFFFFFFu) : ~enc;
    float m = __uint_as_float(bits);
    float e = __expf(gate[i] - m);
    gate[i] = e;
    atomicAdd(&segsum[h * NREACT + j], e);
}

__global__ void phase3_kernel(const float* __restrict__ gate, const int* __restrict__ ridx,
                              const float* __restrict__ segsum, float* __restrict__ out)
{
    int n = blockIdx.x * blockDim.x + threadIdx.x;
    if (n >= NELEM) return;
    int j = ridx[n];
    float s = 0.0f;
#pragma unroll
    for (int h = 0; h < NH; ++h)
        s += gate[h * NELEM + n] / (segsum[h * NREACT + j] + 1e-13f);
    out[n] = s * (1.0f / 3.0f);
}

// ---------------- launcher ----------------
extern "C" void kernel_launch(void* const* d_in, const int* in_sizes, int n_in,
                              void* d_out, int out_size, void* d_ws, size_t ws_size,
                              hipStream_t stream)
{
    const float* elem  = (const float*)d_in[0];
    const int*   ridx  = (const int*)  d_in[1];
    const float* embed = (const float*)d_in[2];
    const float* fcW0  = (const float*)d_in[3];
    const float* fcb0  = (const float*)d_in[4];
    const float* fcW1  = (const float*)d_in[5];
    const float* fcb1  = (const float*)d_in[6];
    const float* fcW2  = (const float*)d_in[7];
    const float* fcb2  = (const float*)d_in[8];
    const float* fcW3  = (const float*)d_in[9];
    const float* fcb3  = (const float*)d_in[10];
    const float* fcW4  = (const float*)d_in[11];
    const float* fcb4  = (const float*)d_in[12];
    const float* fcW5  = (const float*)d_in[13];
    const float* fcb5  = (const float*)d_in[14];
    const float* fcW6  = (const float*)d_in[15];
    const float* fcb6  = (const float*)d_in[16];
    const float* resW0 = (const float*)d_in[17];
    const float* resW4 = (const float*)d_in[18];
    const float* resW6 = (const float*)d_in[19];
    const float* outW  = (const float*)d_in[20];
    const float* outb  = (const float*)d_in[21];

    float*        gate   = (float*)d_ws;                                   // 600000 f32
    unsigned int* segmax = (unsigned int*)d_ws + 600000;                   // 300000 u32
    float*        segsum = (float*)d_ws + 900000;                          // 300000 f32
    unsigned short* wb   = (unsigned short*)((float*)d_ws + 1200000);

    unsigned short* wt_fc0  = wb;              // 3*256*352
    unsigned short* wt_res0 = wb + 270336;
    unsigned short* wt_fc1  = wb + 540672;     // 3*256*256
    unsigned short* wt_fc2  = wb + 737280;
    unsigned short* wt_fc3  = wb + 933888;
    unsigned short* wt_fc4  = wb + 1130496;    // 3*128*256
    unsigned short* wt_res4 = wb + 1228800;
    unsigned short* wt_fc5  = wb + 1327104;    // 3*128*128
    unsigned short* wt_fc6  = wb + 1376256;    // 3*64*128
    unsigned short* wt_res6 = wb + 1400832;

    // zero segmax + segsum
    hipMemsetAsync((void*)segmax, 0, sizeof(unsigned int) * 600000, stream);

    // weight convert/transpose prepass (runs every launch; inputs restored each call)
    wconv_kernel<<<NH * 256, 128, 0, stream>>>(fcW0, wt_fc0, 328, 256, 352);
    wconv_kernel<<<NH * 256, 128, 0, stream>>>(resW0, wt_res0, 328, 256, 352);
    wconv_kernel<<<NH * 256, 128, 0, stream>>>(fcW1, wt_fc1, 256, 256, 256);
    wconv_kernel<<<NH * 256, 128, 0, stream>>>(fcW2, wt_fc2, 256, 256, 256);
    wconv_kernel<<<NH * 256, 128, 0, stream>>>(fcW3, wt_fc3, 256, 256, 256);
    wconv_kernel<<<NH * 128, 128, 0, stream>>>(fcW4, wt_fc4, 256, 128, 256);
    wconv_kernel<<<NH * 128, 128, 0, stream>>>(resW4, wt_res4, 256, 128, 256);
    wconv_kernel<<<NH * 128, 128, 0, stream>>>(fcW5, wt_fc5, 128, 128, 128);
    wconv_kernel<<<NH * 64,  128, 0, stream>>>(fcW6, wt_fc6, 128, 64, 128);
    wconv_kernel<<<NH * 64,  128, 0, stream>>>(resW6, wt_res6, 128, 64, 128);

    dim3 grid(NELEM / MT, NH);
    mlp_mfma<<<grid, NT, 0, stream>>>(elem, ridx, embed,
                                      wt_fc0, wt_res0, wt_fc1, wt_fc2, wt_fc3,
                                      wt_fc4, wt_res4, wt_fc5, wt_fc6, wt_res6,
                                      fcb0, fcb1, fcb2, fcb3, fcb4, fcb5, fcb6,
                                      outW, outb, gate, segmax);

    int tot = NH * NELEM;
    phase2_kernel<<<(tot + 255) / 256, 256, 0, stream>>>(gate, ridx, segmax, segsum);
    phase3_kernel<<<(NELEM + 255) / 256, 256, 0, stream>>>(gate, ridx, segsum, (float*)d_out);
}

// Round 3
// 2188.724 us; speedup vs baseline: 4.4512x; 1.0086x over previous
//
#include <hip/hip_runtime.h>

#define NELEM  200000
#define NREACT 100000
#define EDIM   200
#define RDIM   128
#define F0     328
#define F0PAD  352      // K padded to multiple of 32 for layer 0
#define NH     3
#define MT     64       // rows per block tile (200000/64 = 3125 blocks)
#define NT     256      // 4 waves
#define SA     360      // LDS row stride (elems); 720 B rows, 16B-aligned

typedef _Float16 f16x8 __attribute__((ext_vector_type(8)));
typedef float    f32x4 __attribute__((ext_vector_type(4)));

// ---------------- fused weight convert + transpose prepass ----------------
// src fp32 [H][K][N] -> dst fp16 [H][N][Kpad], zero-padded for k >= K
struct WSeg { const float* src; _Float16* dst; int K, N, Kpad, nb; };
struct WTab { WSeg s[10]; };

__global__ void wconv_all(WTab t)
{
    int b = blockIdx.x;
    for (int i = 0; i < 10; ++i) {
        if (b < t.s[i].nb) {
            const WSeg g = t.s[i];
            int h = b / g.N, n = b - h * g.N;
            const float* sp = g.src + (size_t)h * g.K * g.N + n;
            _Float16* dp = g.dst + (size_t)b * g.Kpad;
            for (int k = threadIdx.x; k < g.Kpad; k += blockDim.x)
                dp[k] = (k < g.K) ? (_Float16)sp[(size_t)k * g.N] : (_Float16)0.f;
            return;
        }
        b -= t.s[i].nb;
    }
}

// ---------------- one MFMA layer, in-place LDS ----------------
// buf: LDS fp16 [MT][SA]; wave computes output cols [n0, n0+TN*16).
// k-loop fully unrolled (compile-time KSTEPS) so B loads pipeline.
// PROJ: projection residual (wRes); IDRES: identity residual from fp32 regs.
template<int TN, int KSTEPS, int KPAD, bool PROJ, bool IDRES>
__device__ __forceinline__ void layer(
    _Float16* __restrict__ buf,
    const _Float16* __restrict__ wFc,
    const _Float16* __restrict__ wRes,
    const float* __restrict__ bias,
    int n0, f32x4 prev[4][4], int lane)
{
    const int r = lane & 15, q = lane >> 4;
    f32x4 acc[4][TN];
    f32x4 racc[4][TN];
#pragma unroll
    for (int mt = 0; mt < 4; ++mt)
#pragma unroll
        for (int nt = 0; nt < TN; ++nt) {
            acc[mt][nt] = (f32x4){0.f, 0.f, 0.f, 0.f};
            if constexpr (PROJ) racc[mt][nt] = (f32x4){0.f, 0.f, 0.f, 0.f};
        }

    const _Float16* aBase  = buf + r * SA + q * 8;
    const _Float16* wBase  = wFc + ((size_t)n0 + r) * KPAD + q * 8;
    const _Float16* wrBase = PROJ ? (wRes + ((size_t)n0 + r) * KPAD + q * 8) : nullptr;

#pragma unroll
    for (int kt = 0; kt < KSTEPS; ++kt) {
        f16x8 a[4];
#pragma unroll
        for (int mt = 0; mt < 4; ++mt)
            a[mt] = *(const f16x8*)(aBase + mt * 16 * SA + kt * 32);
#pragma unroll
        for (int nt = 0; nt < TN; ++nt) {
            f16x8 b = *(const f16x8*)(wBase + (size_t)nt * 16 * KPAD + kt * 32);
#pragma unroll
            for (int mt = 0; mt < 4; ++mt)
                acc[mt][nt] = __builtin_amdgcn_mfma_f32_16x16x32_f16(a[mt], b, acc[mt][nt], 0, 0, 0);
            if constexpr (PROJ) {
                f16x8 br = *(const f16x8*)(wrBase + (size_t)nt * 16 * KPAD + kt * 32);
#pragma unroll
                for (int mt = 0; mt < 4; ++mt)
                    racc[mt][nt] = __builtin_amdgcn_mfma_f32_16x16x32_f16(a[mt], br, racc[mt][nt], 0, 0, 0);
            }
        }
    }

    __syncthreads();   // all waves' LDS reads complete before in-place write

    // C/D layout: col = lane&15 (r), row = q*4 + i (+mt*16)
#pragma unroll
    for (int nt = 0; nt < TN; ++nt) {
        float b = bias[n0 + nt * 16 + r];
#pragma unroll
        for (int mt = 0; mt < 4; ++mt) {
#pragma unroll
            for (int i = 0; i < 4; ++i) {
                float z = fmaxf(acc[mt][nt][i] + b, 0.f);
                if constexpr (PROJ)       z += racc[mt][nt][i];
                else if constexpr (IDRES) z += prev[mt][nt][i];
                prev[mt][nt][i] = z;           // residual trunk stays fp32
                int m = mt * 16 + q * 4 + i;
                buf[m * SA + n0 + nt * 16 + r] = (_Float16)z;
            }
        }
    }
}

// ---------------- fused MLP kernel ----------------
__global__ __launch_bounds__(NT, 3)
void mlp_mfma(const float* __restrict__ elem, const int* __restrict__ ridx,
              const float* __restrict__ embed,
              const _Float16* __restrict__ wb,
              const float* __restrict__ fcb0, const float* __restrict__ fcb1,
              const float* __restrict__ fcb2, const float* __restrict__ fcb3,
              const float* __restrict__ fcb4, const float* __restrict__ fcb5,
              const float* __restrict__ fcb6,
              const float* __restrict__ outW, const float* __restrict__ outb,
              float* __restrict__ gate, unsigned int* __restrict__ segmax)
{
    __shared__ __align__(16) _Float16 sX[MT * SA];   // 46080 B, in-place all layers
    __shared__ int sidx[MT];

    const int tid = threadIdx.x, lane = tid & 63, wave = tid >> 6;
    const int head = blockIdx.y;
    const int row0 = blockIdx.x * MT;

    if (tid < MT) sidx[tid] = ridx[row0 + tid];
    __syncthreads();

    // stage concat(elem, embed[idx]) -> fp16, zero-pad k in [328,352)
    for (int rr = wave; rr < MT; rr += 4) {
        const float* es = elem + (size_t)(row0 + rr) * EDIM;
        const float* ms = embed + (size_t)sidx[rr] * RDIM;
        for (int k = lane; k < F0PAD; k += 64) {
            float v = (k < EDIM) ? es[k] : (k < F0 ? ms[k - EDIM] : 0.f);
            sX[rr * SA + k] = (_Float16)v;
        }
    }
    __syncthreads();

    const size_t h = head;
    f32x4 prev[4][4];
    const int n64 = wave * 64, n32 = wave * 32, n16 = wave * 16;

    // weight blob offsets (fp16 elems)
    const _Float16* wt_fc0  = wb;
    const _Float16* wt_res0 = wb + 270336;
    const _Float16* wt_fc1  = wb + 540672;
    const _Float16* wt_fc2  = wb + 737280;
    const _Float16* wt_fc3  = wb + 933888;
    const _Float16* wt_fc4  = wb + 1130496;
    const _Float16* wt_res4 = wb + 1228800;
    const _Float16* wt_fc5  = wb + 1327104;
    const _Float16* wt_fc6  = wb + 1376256;
    const _Float16* wt_res6 = wb + 1400832;

    layer<4, 11, 352, true , false>(sX, wt_fc0 + h * 90112, wt_res0 + h * 90112,
                                    fcb0 + h * 256, n64, prev, lane);
    __syncthreads();
    layer<4, 8, 256, false, true >(sX, wt_fc1 + h * 65536, nullptr,
                                   fcb1 + h * 256, n64, prev, lane);
    __syncthreads();
    layer<4, 8, 256, false, true >(sX, wt_fc2 + h * 65536, nullptr,
                                   fcb2 + h * 256, n64, prev, lane);
    __syncthreads();
    layer<4, 8, 256, false, true >(sX, wt_fc3 + h * 65536, nullptr,
                                   fcb3 + h * 256, n64, prev, lane);
    __syncthreads();
    layer<2, 8, 256, true , false>(sX, wt_fc4 + h * 32768, wt_res4 + h * 32768,
                                   fcb4 + h * 128, n32, prev, lane);
    __syncthreads();
    layer<2, 4, 128, false, true >(sX, wt_fc5 + h * 16384, nullptr,
                                   fcb5 + h * 128, n32, prev, lane);
    __syncthreads();
    layer<1, 4, 128, true , false>(sX, wt_fc6 + h * 8192, wt_res6 + h * 8192,
                                   fcb6 + h * 64, n16, prev, lane);
    __syncthreads();

    // gate = h64 . outW + outb ; one thread per row
    if (tid < MT) {
        const _Float16* hv = sX + tid * SA;
        const float* wv = outW + h * 64;
        float g = outb[head];
#pragma unroll
        for (int f = 0; f < 64; ++f) g = fmaf((float)hv[f], wv[f], g);
        gate[head * NELEM + row0 + tid] = g;
        unsigned int bits = __float_as_uint(g);
        unsigned int enc  = (bits & 0x80000000u) ? ~bits : (bits | 0x80000000u);
        atomicMax(&segmax[head * NREACT + sidx[tid]], enc);
    }
}

// ---------------- softmax phases ----------------
__global__ void phase2_kernel(float* __restrict__ gate, const int* __restrict__ ridx,
                              const unsigned int* __restrict__ segmax,
                              float* __restrict__ segsum)
{
    int i = blockIdx.x * blockDim.x + threadIdx.x;
    if (i >= NH * NELEM) return;
    int h = i / NELEM;
    int n = i - h * NELEM;
    int j = ridx[n];
    unsigned int enc  = segmax[h * NREACT + j];
    unsigned int bits = (enc & 0x80000000u) ? (enc & 0x7FFFFFFFu) : ~enc;
    float m = __uint_as_float(bits);
    float e = __expf(gate[i] - m);
    gate[i] = e;
    atomicAdd(&segsum[h * NREACT + j], e);
}

__global__ void phase3_kernel(const float* __restrict__ gate, const int* __restrict__ ridx,
                              const float* __restrict__ segsum, float* __restrict__ out)
{
    int n = blockIdx.x * blockDim.x + threadIdx.x;
    if (n >= NELEM) return;
    int j = ridx[n];
    float s = 0.0f;
#pragma unroll
    for (int h = 0; h < NH; ++h)
        s += gate[h * NELEM + n] / (segsum[h * NREACT + j] + 1e-13f);
    out[n] = s * (1.0f / 3.0f);
}

// ---------------- launcher ----------------
extern "C" void kernel_launch(void* const* d_in, const int* in_sizes, int n_in,
                              void* d_out, int out_size, void* d_ws, size_t ws_size,
                              hipStream_t stream)
{
    const float* elem  = (const float*)d_in[0];
    const int*   ridx  = (const int*)  d_in[1];
    const float* embed = (const float*)d_in[2];
    const float* fcW0  = (const float*)d_in[3];
    const float* fcb0  = (const float*)d_in[4];
    const float* fcW1  = (const float*)d_in[5];
    const float* fcb1  = (const float*)d_in[6];
    const float* fcW2  = (const float*)d_in[7];
    const float* fcb2  = (const float*)d_in[8];
    const float* fcW3  = (const float*)d_in[9];
    const float* fcb3  = (const float*)d_in[10];
    const float* fcW4  = (const float*)d_in[11];
    const float* fcb4  = (const float*)d_in[12];
    const float* fcW5  = (const float*)d_in[13];
    const float* fcb5  = (const float*)d_in[14];
    const float* fcW6  = (const float*)d_in[15];
    const float* fcb6  = (const float*)d_in[16];
    const float* resW0 = (const float*)d_in[17];
    const float* resW4 = (const float*)d_in[18];
    const float* resW6 = (const float*)d_in[19];
    const float* outW  = (const float*)d_in[20];
    const float* outb  = (const float*)d_in[21];

    float*        gate   = (float*)d_ws;                  // 600000 f32
    unsigned int* segmax = (unsigned int*)d_ws + 600000;  // 300000 u32
    float*        segsum = (float*)d_ws + 900000;         // 300000 f32
    _Float16*     wbuf   = (_Float16*)((float*)d_ws + 1200000);

    hipMemsetAsync((void*)segmax, 0, sizeof(unsigned int) * 600000, stream);

    WTab t;
    t.s[0] = { fcW0,  wbuf,           328, 256, 352, 768 };
    t.s[1] = { resW0, wbuf + 270336,  328, 256, 352, 768 };
    t.s[2] = { fcW1,  wbuf + 540672,  256, 256, 256, 768 };
    t.s[3] = { fcW2,  wbuf + 737280,  256, 256, 256, 768 };
    t.s[4] = { fcW3,  wbuf + 933888,  256, 256, 256, 768 };
    t.s[5] = { fcW4,  wbuf + 1130496, 256, 128, 256, 384 };
    t.s[6] = { resW4, wbuf + 1228800, 256, 128, 256, 384 };
    t.s[7] = { fcW5,  wbuf + 1327104, 128, 128, 128, 384 };
    t.s[8] = { fcW6,  wbuf + 1376256, 128,  64, 128, 192 };
    t.s[9] = { resW6, wbuf + 1400832, 128,  64, 128, 192 };
    wconv_all<<<5376, 128, 0, stream>>>(t);

    dim3 grid(NELEM / MT, NH);
    mlp_mfma<<<grid, NT, 0, stream>>>(elem, ridx, embed, wbuf,
                                      fcb0, fcb1, fcb2, fcb3, fcb4, fcb5, fcb6,
                                      outW, outb, gate, segmax);

    int tot = NH * NELEM;
    phase2_kernel<<<(tot + 255) / 256, 256, 0, stream>>>(gate, ridx, segmax, segsum);
    phase3_kernel<<<(NELEM + 255) / 256, 256, 0, stream>>>(gate, ridx, segsum, (float*)d_out);
}